// Round 7
// baseline (106.536 us; speedup 1.0000x reference)
//
#include <hip/hip_runtime.h>
#include <math.h>

// RESUS_NN_2327872274812: Q=8192, S=30, D=512.
// Wave w: 4 queries, d-half p=w&1 (256 floats). lane=(h,s): h = 128-float
// quarter within the half, s = support row. 16 j-steps x 8 d.
// - 4096 waves total = 4 waves/SIMD (512 blocks x 8 waves, 2 blocks/CU),
//   doubling r6's occupancy while keeping QPW=4 traffic efficiency.
// - support in LDS, RS=513 (odd): main-loop ds_read_b32 bank = (s+8j+e)%32,
//   injective over s, 2-way h-alias = free (m136). Clamped s>=30 lanes read
//   row 29's exact address = broadcast merge.
// - query/w: 2-distinct-address global loads per instr, distance-1 prefetch.
// - p-halves merged via one-time ds_add_f32 into part[16][30] float2
//   (2 commutative adds per slot -> bit-deterministic).
// - Epilogue: 16 x 32-lane groups, one query each, shuffle softmax.

#define QN 8192
#define SN 30
#define DN 512
#define BLK 512
#define QPB 16           // queries per block
#define RS 513           // support LDS row stride (odd -> conflict-free)

__global__ __launch_bounds__(BLK, 4)
void resus_one(const float* __restrict__ query,      // [Q][D]
               const float* __restrict__ support,    // [S][D]
               const float* __restrict__ support_y,  // [S]
               const float* __restrict__ support_pr, // [S]
               const float* __restrict__ query_pr,   // [Q]
               const float* __restrict__ fc1_w,      // [D]
               const float* __restrict__ adj_scale,  // [30]
               const float* __restrict__ adj_bias,   // [30]
               const int*   __restrict__ num_samples,// [1]
               float* __restrict__ out)              // [2*Q]
{
    __shared__ float  s_lds[SN * RS];   // 61,560 B
    __shared__ float2 part[QPB * SN];   //  3,840 B  (sc, sq) per (q, s)

    const int tid  = threadIdx.x;
    const int lane = tid & 63;
    const int wv   = tid >> 6;           // 0..7
    const int p    = wv & 1;             // d-half of this wave
    const int h    = lane >> 5;          // d-quarter within the half
    const int s    = lane & 31;          // support row (valid < 30)
    const int srow_i = (s < SN) ? s : (SN - 1);

    const int qbase = blockIdx.x * QPB + (wv >> 1) * 4;
    const int doff  = p * 256 + h * 128;

    const float* qr0 = query + (size_t)(qbase + 0) * DN + doff;
    const float* qr1 = query + (size_t)(qbase + 1) * DN + doff;
    const float* qr2 = query + (size_t)(qbase + 2) * DN + doff;
    const float* qr3 = query + (size_t)(qbase + 3) * DN + doff;
    const float* wr  = fc1_w + doff;
    const float* srow = s_lds + srow_i * RS + doff;

    // ---- prologue prefetch (j = 0), before staging/barrier ----
    float4 c0a = *reinterpret_cast<const float4*>(qr0);
    float4 c0b = *reinterpret_cast<const float4*>(qr0 + 4);
    float4 c1a = *reinterpret_cast<const float4*>(qr1);
    float4 c1b = *reinterpret_cast<const float4*>(qr1 + 4);
    float4 c2a = *reinterpret_cast<const float4*>(qr2);
    float4 c2b = *reinterpret_cast<const float4*>(qr2 + 4);
    float4 c3a = *reinterpret_cast<const float4*>(qr3);
    float4 c3b = *reinterpret_cast<const float4*>(qr3 + 4);
    float4 cwa = *reinterpret_cast<const float4*>(wr);
    float4 cwb = *reinterpret_cast<const float4*>(wr + 4);

    // ---- stage support (coalesced float4 -> b32 scatter) + zero partials ----
    {
        const float4* sg = reinterpret_cast<const float4*>(support);
        for (int i = tid; i < SN * (DN / 4); i += BLK) {
            const float4 v = sg[i];
            float* d = s_lds + (i >> 7) * RS + 4 * (i & 127);
            d[0] = v.x; d[1] = v.y; d[2] = v.z; d[3] = v.w;
        }
        float* pf = reinterpret_cast<float*>(part);
        for (int i = tid; i < QPB * SN * 2; i += BLK) pf[i] = 0.0f;
    }
    __syncthreads();

    float sc0 = 0.f, sq0 = 0.f, sc1 = 0.f, sq1 = 0.f;
    float sc2 = 0.f, sq2 = 0.f, sc3 = 0.f, sq3 = 0.f;

#define ACC8(CA, CB, SC, SQ) { float d_; \
    d_ = (CA).x - s0; SC = fmaf(cwa.x, fabsf(d_), SC); SQ = fmaf(d_, d_, SQ); \
    d_ = (CA).y - s1; SC = fmaf(cwa.y, fabsf(d_), SC); SQ = fmaf(d_, d_, SQ); \
    d_ = (CA).z - s2; SC = fmaf(cwa.z, fabsf(d_), SC); SQ = fmaf(d_, d_, SQ); \
    d_ = (CA).w - s3; SC = fmaf(cwa.w, fabsf(d_), SC); SQ = fmaf(d_, d_, SQ); \
    d_ = (CB).x - s4; SC = fmaf(cwb.x, fabsf(d_), SC); SQ = fmaf(d_, d_, SQ); \
    d_ = (CB).y - s5; SC = fmaf(cwb.y, fabsf(d_), SC); SQ = fmaf(d_, d_, SQ); \
    d_ = (CB).z - s6; SC = fmaf(cwb.z, fabsf(d_), SC); SQ = fmaf(d_, d_, SQ); \
    d_ = (CB).w - s7; SC = fmaf(cwb.w, fabsf(d_), SC); SQ = fmaf(d_, d_, SQ); }

#pragma unroll
    for (int j = 0; j < 16; ++j) {       // 8 d per step, 128 d total
        const int jn = (j + 1) & 15;     // wraps at j=15 (in-bounds, unused)
        float4 n0a = *reinterpret_cast<const float4*>(qr0 + 8 * jn);
        float4 n0b = *reinterpret_cast<const float4*>(qr0 + 8 * jn + 4);
        float4 n1a = *reinterpret_cast<const float4*>(qr1 + 8 * jn);
        float4 n1b = *reinterpret_cast<const float4*>(qr1 + 8 * jn + 4);
        float4 n2a = *reinterpret_cast<const float4*>(qr2 + 8 * jn);
        float4 n2b = *reinterpret_cast<const float4*>(qr2 + 8 * jn + 4);
        float4 n3a = *reinterpret_cast<const float4*>(qr3 + 8 * jn);
        float4 n3b = *reinterpret_cast<const float4*>(qr3 + 8 * jn + 4);
        float4 nwa = *reinterpret_cast<const float4*>(wr + 8 * jn);
        float4 nwb = *reinterpret_cast<const float4*>(wr + 8 * jn + 4);

        const float* sp = srow + 8 * j;  // 2-way bank alias: free
        const float s0 = sp[0], s1 = sp[1], s2 = sp[2], s3 = sp[3];
        const float s4 = sp[4], s5 = sp[5], s6 = sp[6], s7 = sp[7];

        ACC8(c0a, c0b, sc0, sq0)
        ACC8(c1a, c1b, sc1, sq1)
        ACC8(c2a, c2b, sc2, sq2)
        ACC8(c3a, c3b, sc3, sq3)

        c0a = n0a; c0b = n0b; c1a = n1a; c1b = n1b;
        c2a = n2a; c2b = n2b; c3a = n3a; c3b = n3b;
        cwa = nwa; cwb = nwb;
    }
#undef ACC8

    // ---- combine h-quarters (lane ^ 32 = same s, other quarter) ----
    sc0 += __shfl_xor(sc0, 32); sq0 += __shfl_xor(sq0, 32);
    sc1 += __shfl_xor(sc1, 32); sq1 += __shfl_xor(sq1, 32);
    sc2 += __shfl_xor(sc2, 32); sq2 += __shfl_xor(sq2, 32);
    sc3 += __shfl_xor(sc3, 32); sq3 += __shfl_xor(sq3, 32);

    // ---- merge p-halves: one-time ds_add_f32 (2 adds/slot, deterministic) ----
    if (h == 0 && s < SN) {
        const int qloc = (wv >> 1) * 4;
        atomicAdd(&part[(qloc + 0) * SN + s].x, sc0);
        atomicAdd(&part[(qloc + 0) * SN + s].y, sq0);
        atomicAdd(&part[(qloc + 1) * SN + s].x, sc1);
        atomicAdd(&part[(qloc + 1) * SN + s].y, sq1);
        atomicAdd(&part[(qloc + 2) * SN + s].x, sc2);
        atomicAdd(&part[(qloc + 2) * SN + s].y, sq2);
        atomicAdd(&part[(qloc + 3) * SN + s].x, sc3);
        atomicAdd(&part[(qloc + 3) * SN + s].y, sq3);
    }
    __syncthreads();

    // ---- epilogue: 16 groups of 32 lanes, one query each ----
    const int  qloc  = 2 * wv + h;                   // 0..15
    const int  q     = blockIdx.x * QPB + qloc;
    const bool valid = (s < SN);
    const float2 pr  = part[qloc * SN + (valid ? s : 0)];

    float scv = valid ? pr.x : -1e30f;
    float ssv = valid ? pr.y : 0.f;
    float dy  = 0.f;
    if (valid)
        dy = support_y[s] - 1.0f / (1.0f + expf(-support_pr[s]));

    float m = scv;
#pragma unroll
    for (int off = 16; off >= 1; off >>= 1)
        m = fmaxf(m, __shfl_xor(m, off));

    float e   = valid ? expf(scv - m) : 0.f;
    float den = e;
    float num = dy * e;
    float l2  = valid ? sqrtf(ssv) : 0.f;
#pragma unroll
    for (int off = 16; off >= 1; off >>= 1) {
        den += __shfl_xor(den, off);
        num += __shfl_xor(num, off);
        l2  += __shfl_xor(l2,  off);
    }

    if (s == 0) {
        const int ns = num_samples[0];
        const float scale = fabsf(adj_scale[ns - 1]);
        const float bias  = adj_bias[ns - 1];
        out[q]      = num / den * scale + bias + query_pr[q];
        out[QN + q] = l2 * (1.0f / (float)SN);
    }
}

extern "C" void kernel_launch(void* const* d_in, const int* in_sizes, int n_in,
                              void* d_out, int out_size, void* d_ws, size_t ws_size,
                              hipStream_t stream)
{
    const float* query      = (const float*)d_in[0];
    const float* support    = (const float*)d_in[1];
    const float* support_y  = (const float*)d_in[2];
    const float* support_pr = (const float*)d_in[3];
    const float* query_pr   = (const float*)d_in[4];
    const float* fc1_w      = (const float*)d_in[5];
    // d_in[6] = fc1_b: cancels in softmax, unused
    const float* adj_scale  = (const float*)d_in[7];
    const float* adj_bias   = (const float*)d_in[8];
    const int*   num_s      = (const int*)d_in[9];
    float* out = (float*)d_out;

    dim3 grid(QN / QPB);     // 512 blocks, 2 per CU -> 4 waves/SIMD
    hipLaunchKernelGGL(resus_one, grid, dim3(BLK), 0, stream,
                       query, support, support_y, support_pr, query_pr,
                       fc1_w, adj_scale, adj_bias, num_s, out);
}